// Round 11
// baseline (82.667 us; speedup 1.0000x reference)
//
#include <hip/hip_runtime.h>

// Problem constants
#define BB 8
#define CI 64
#define CO 64
#define NV 40962
#define KN 7
#define KKD 448   // CI*KN
#define NTILES 641   // ceil(NV/64)
#define BPB 64       // blocks per batch (grid = 8*BPB)

typedef unsigned short u16;
typedef unsigned int u32;

typedef __bf16 bf16x8 __attribute__((ext_vector_type(8)));
typedef float f32x16 __attribute__((ext_vector_type(16)));

#define WAITV(N) asm volatile("s_waitcnt vmcnt(" #N ")" ::: "memory")

__device__ inline u16 f2bf(float f) {
    u32 u = __builtin_bit_cast(u32, f);
    u32 r = (u + 0x7FFFu + ((u >> 16) & 1u)) >> 16;  // RNE
    return (u16)r;
}

// global 16B/lane -> LDS at (wave-uniform base + lane*16); dest linear.
__device__ inline void gload_lds16(const void* g, void* l) {
    __builtin_amdgcn_global_load_lds(
        (const __attribute__((address_space(1))) u32*)g,
        (__attribute__((address_space(3))) u32*)l, 16, 0, 0);
}

// ---------------------------------------------------------------------------
// Kernel 1: transpose + bf16 cast:  x[b][c][n] f32  ->  xT[b][n][c] bf16
// ---------------------------------------------------------------------------
__global__ void transpose_x(const float* __restrict__ x, u16* __restrict__ xT) {
    __shared__ u16 tile[64][72];
    const int b = blockIdx.y;
    const int n0 = blockIdx.x * 64;
    const int tid = threadIdx.x;

#pragma unroll
    for (int i = 0; i < 16; ++i) {
        int flat = i * 256 + tid;
        int c = flat >> 6;
        int nn = flat & 63;
        int n = n0 + nn;
        if (n < NV) {
            float v = __builtin_nontemporal_load(&x[((size_t)b * CI + c) * NV + n]);
            tile[nn][c] = f2bf(v);
        }
    }
    __syncthreads();

#pragma unroll
    for (int i = 0; i < 2; ++i) {
        int flat8 = i * 256 + tid;
        int nn = flat8 >> 3;
        int c0 = (flat8 & 7) * 8;
        int n = n0 + nn;
        if (n < NV) {
            uint4 v = *(const uint4*)&tile[nn][c0];
            *(uint4*)&xT[((size_t)b * NV + n) * CI + c0] = v;
        }
    }
}

// ---------------------------------------------------------------------------
// Kernel 2: pack W into MFMA A-fragment order (bf16)
// Wf byte offset (rg*28 + k*4 + sub)*1024 + lane*16
// ---------------------------------------------------------------------------
__global__ void pack_w(const float* __restrict__ W, u16* __restrict__ Wf) {
    int e = blockIdx.x * 256 + threadIdx.x;
    if (e < 2 * 28 * 64 * 8) {
        int j = e & 7;
        int lane = (e >> 3) & 63;
        int sg = e >> 9;
        int s = sg % 28;
        int rg = sg / 28;
        int o = rg * 32 + (lane & 31);
        int kk = s * 16 + ((lane >> 5) << 3) + j;
        int kn = kk >> 6;
        int c = kk & 63;
        Wf[e] = f2bf(W[o * KKD + c * KN + kn]);
    }
}

// ---------------------------------------------------------------------------
// Kernel 3: A-HOISTED PERSISTENT gather+MFMA pipeline.
// grid 512 (= 2 blocks/CU), block 256 = 4 waves (rg = w&1, cg = w>>1).
// b = bid&7 (XCD pin: all 64 blocks of batch b co-resident on one XCD),
// block handles tiles tile0 + 64g (64-vertex tiles), ring-3 x 8KB LDS flows
// seamlessly ACROSS tiles (no drain except kernel end).
//
// Key change vs r10: all 28 A-fragments (this wave's rg) hoisted to VGPRs
// once per block -> per-iter VMEM drops 12 -> 2 (A-stream was ~575 MB of L2
// reads for a 57 KB table; L1 thrashed by wave drift). Bias hoisted too, so
// the epilogue is exactly 16 stores -> vmcnt ladder stays exactly countable.
//
// Per iter k: WAIT(ladder) -> s_barrier -> stage G into slot (ring+k+2)%3
// [k<=4: this tile's k+2; k=5,6: next tile's k=0,1] -> [k==0: load idx of
// next tile] -> 4x(ds_read+MFMA) on slot (ring+k)%3.
// Ladder (per-wave queue exactly): first tile [2,6,6,2,2,2,2];
// later tiles [18,22,6,2,2,2,2] (epilogue S16 + G0'2 + G1'2 in queue).
// WAR proof (r6): stage-after-barrier(k) targets the slot read at k-1,
// whose ds_reads completed before their MFMAs, which preceded barrier(k).
// Partial tile (640) is always a block's LAST tile -> predicated epilogue
// cannot perturb any later wait.
// ---------------------------------------------------------------------------
__global__ __launch_bounds__(256, 2) void conv_mfma(
    const u16* __restrict__ xT, const u16* __restrict__ Wf,
    const int* __restrict__ idx, const float* __restrict__ bias,
    float* __restrict__ out) {
    __shared__ alignas(16) u16 G[3][4096];   // ring-3 x 8KB (64 rows x 128B)

    const int bid = blockIdx.x;
    const int b = bid & 7;
    const int tile0 = bid >> 3;          // 0..63
    const int t = threadIdx.x;
    const int lane = t & 63;
    const int w = t >> 6;                // 0..3
    const int rg = w & 1;
    const int cg = w >> 1;               // 0..1
    const int col = lane & 31;
    const int half = lane >> 5;

    const char* xbc = (const char*)(xT + (size_t)b * NV * CI);
    const char* wfc = (const char*)Wf;
    char* gb = (char*)&G[0][0];

    // staging geometry: thread covers rows sr0 and 32+sr0, chunk q
    const int sr0 = t >> 3;              // 0..31
    const int q = t & 7;
    const u32 qe16 = (u32)((q ^ (sr0 & 7)) << 4);   // source pre-swizzle
    const u32 dst0 = (u32)(w * 1024);
    const u32 dst1 = (u32)(4096 + w * 1024);

    // B-read geometry
    const int brow = cg * 32 + col;      // 0..63
    const u32 rbase = (u32)(brow * 128);
    const u32 rmask = (u32)(brow & 7) << 4;

    // ---- prologue VMEM, order pinned: idx(t0), bias, A[28], G(0), G(1) ----
    int jc0[KN], jc1[KN], jn0[KN], jn1[KN];
    {
        int nn0 = tile0 * 64 + sr0;      if (nn0 >= NV) nn0 = NV - 1;
        int nn1 = tile0 * 64 + 32 + sr0; if (nn1 >= NV) nn1 = NV - 1;
        int4 lo0 = *(const int4*)(idx + (size_t)nn0 * KN);
        int4 hi0 = *(const int4*)(idx + (size_t)nn0 * KN + 3);
        int4 lo1 = *(const int4*)(idx + (size_t)nn1 * KN);
        int4 hi1 = *(const int4*)(idx + (size_t)nn1 * KN + 3);
        jc0[0]=lo0.x; jc0[1]=lo0.y; jc0[2]=lo0.z; jc0[3]=lo0.w;
        jc0[4]=hi0.y; jc0[5]=hi0.z; jc0[6]=hi0.w;
        jc1[0]=lo1.x; jc1[1]=lo1.y; jc1[2]=lo1.z; jc1[3]=lo1.w;
        jc1[4]=hi1.y; jc1[5]=hi1.z; jc1[6]=hi1.w;
    }
    float bv[16];
#pragma unroll
    for (int r = 0; r < 16; ++r) {
        int rowo = (r & 3) + 8 * (r >> 2) + 4 * half;
        bv[r] = bias[rg * 32 + rowo];
    }
    uint4 A[28];
#pragma unroll
    for (int s = 0; s < 28; ++s)
        A[s] = *(const uint4*)(wfc + (u32)((rg * 28 + s) * 1024) + (u32)(lane * 16));
    __builtin_amdgcn_sched_barrier(0);
    gload_lds16(xbc + (size_t)jc0[0] * 128 + qe16, gb + 0 * 8192 + dst0);
    gload_lds16(xbc + (size_t)jc1[0] * 128 + qe16, gb + 0 * 8192 + dst1);
    gload_lds16(xbc + (size_t)jc0[1] * 128 + qe16, gb + 1 * 8192 + dst0);
    gload_lds16(xbc + (size_t)jc1[1] * 128 + qe16, gb + 1 * 8192 + dst1);
    __builtin_amdgcn_sched_barrier(0);

    f32x16 acc;
#pragma unroll
    for (int i = 0; i < 16; ++i) acc[i] = 0.f;

    int tcur = tile0;
    int ring = 0;
    bool first = true;

    while (true) {
        const int n0 = tcur * 64;
        int tnxt = tcur + BPB;
        const bool last = (tnxt >= NTILES);
        if (last) tnxt = tcur;           // dummy reload; G' lands in dead slots

#pragma unroll
        for (int k = 0; k < KN; ++k) {
            // ---- exactly-counted per-wave wait, then barrier ----
            if (k == 0)      { if (first) WAITV(2);  else WAITV(18); }
            else if (k == 1) { if (first) WAITV(6);  else WAITV(22); }
            else if (k == 2) WAITV(6);
            else             WAITV(2);
            __builtin_amdgcn_sched_barrier(0);
            __builtin_amdgcn_s_barrier();
            __builtin_amdgcn_sched_barrier(0);

            // ---- stage into slot (ring + k + 2) % 3 ----
            {
                int slot = ring + ((k + 2) % 3); if (slot >= 3) slot -= 3;
                char* d = gb + (u32)slot * 8192u;
                if (k <= 4) {
                    gload_lds16(xbc + (size_t)jc0[k + 2] * 128 + qe16, d + dst0);
                    gload_lds16(xbc + (size_t)jc1[k + 2] * 128 + qe16, d + dst1);
                } else {
                    gload_lds16(xbc + (size_t)jn0[k - 5] * 128 + qe16, d + dst0);
                    gload_lds16(xbc + (size_t)jn1[k - 5] * 128 + qe16, d + dst1);
                }
            }
            if (k == 0) {   // idx for next tile (4 VMEM, in the ladder)
                int nn0 = tnxt * 64 + sr0;      if (nn0 >= NV) nn0 = NV - 1;
                int nn1 = tnxt * 64 + 32 + sr0; if (nn1 >= NV) nn1 = NV - 1;
                int4 lo0 = *(const int4*)(idx + (size_t)nn0 * KN);
                int4 hi0 = *(const int4*)(idx + (size_t)nn0 * KN + 3);
                int4 lo1 = *(const int4*)(idx + (size_t)nn1 * KN);
                int4 hi1 = *(const int4*)(idx + (size_t)nn1 * KN + 3);
                jn0[0]=lo0.x; jn0[1]=lo0.y; jn0[2]=lo0.z; jn0[3]=lo0.w;
                jn0[4]=hi0.y; jn0[5]=hi0.z; jn0[6]=hi0.w;
                jn1[0]=lo1.x; jn1[1]=lo1.y; jn1[2]=lo1.z; jn1[3]=lo1.w;
                jn1[4]=hi1.y; jn1[5]=hi1.z; jn1[6]=hi1.w;
            }
            __builtin_amdgcn_sched_barrier(0);

            // ---- compute slot (ring + k) % 3: 4 x (ds_read + MFMA) ----
            {
                int slot = ring + (k % 3); if (slot >= 3) slot -= 3;
                const char* gsrc = gb + (u32)slot * 8192u;
#pragma unroll
                for (int s = 0; s < 4; ++s) {
                    u32 boff = rbase + ((((u32)s * 32) + (u32)half * 16) ^ rmask);
                    uint4 bf = *(const uint4*)(gsrc + boff);
                    acc = __builtin_amdgcn_mfma_f32_32x32x16_bf16(
                        __builtin_bit_cast(bf16x8, A[k * 4 + s]),
                        __builtin_bit_cast(bf16x8, bf), acc, 0, 0, 0);
                }
            }
        }

        // ---- epilogue: exactly 16 stores (bias pre-hoisted) ----
        {
            const int v = n0 + cg * 32 + col;
            if (v < NV) {   // uniform-true for all non-final tiles
                float* ob = out + (size_t)b * CO * NV + v;
#pragma unroll
                for (int r = 0; r < 16; ++r) {
                    int rowo = (r & 3) + 8 * (r >> 2) + 4 * half;
                    ob[(size_t)(rg * 32 + rowo) * NV] = acc[r] + bv[r];
                }
            }
        }
        if (last) break;
#pragma unroll
        for (int i = 0; i < KN; ++i) { jc0[i] = jn0[i]; jc1[i] = jn1[i]; }
#pragma unroll
        for (int i = 0; i < 16; ++i) acc[i] = 0.f;
        tcur = tnxt;
        ring = ring + 1; if (ring >= 3) ring = 0;   // 7 mod 3 == 1
        first = false;
    }
}

// ---------------------------------------------------------------------------
// Fallback (if ws too small): direct fp32 compute, slow but correct.
// ---------------------------------------------------------------------------
__global__ void naive_conv(const float* __restrict__ x, const int* __restrict__ idx,
                           const float* __restrict__ W, const float* __restrict__ bias,
                           float* __restrict__ out) {
    const int b = blockIdx.y;
    const int n = blockIdx.x * 4 + (threadIdx.x & 3);
    const int o = threadIdx.x >> 2;
    if (n >= NV) return;
    float acc = bias[o];
    const float* xb = x + (size_t)b * CI * NV;
    const float* wo = W + o * KKD;
    for (int k = 0; k < KN; ++k) {
        int j = idx[n * KN + k];
        for (int c = 0; c < CI; ++c)
            acc += xb[(size_t)c * NV + j] * wo[c * KN + k];
    }
    out[((size_t)b * CO + o) * NV + n] = acc;
}

// ---------------------------------------------------------------------------
extern "C" void kernel_launch(void* const* d_in, const int* in_sizes, int n_in,
                              void* d_out, int out_size, void* d_ws, size_t ws_size,
                              hipStream_t stream) {
    const float* x    = (const float*)d_in[0];
    const int*   idx  = (const int*)d_in[1];
    const float* W    = (const float*)d_in[2];
    const float* bias = (const float*)d_in[3];
    float* out = (float*)d_out;

    const size_t xT_bytes = (size_t)BB * NV * CI * 2;       // 41,945,088
    const size_t wf_bytes = (size_t)2 * 28 * 64 * 8 * 2;    // 57,344
    const size_t need = xT_bytes + wf_bytes;

    if (ws_size >= need) {
        u16* xT = (u16*)d_ws;
        u16* Wf = (u16*)((char*)d_ws + xT_bytes);
        transpose_x<<<dim3((NV + 63) / 64, BB), 256, 0, stream>>>(x, xT);
        pack_w<<<dim3(112), 256, 0, stream>>>(W, Wf);
        conv_mfma<<<dim3(8 * BPB), 256, 0, stream>>>(xT, Wf, idx, bias, out);
    } else {
        naive_conv<<<dim3((NV + 3) / 4, BB), 256, 0, stream>>>(x, idx, W, bias, out);
    }
}

// Round 12
// 79.273 us; speedup vs baseline: 1.0428x; 1.0428x over previous
//
#include <hip/hip_runtime.h>

// Problem constants
#define BB 8
#define CI 64
#define CO 64
#define NV 40962
#define KN 7
#define KKD 448   // CI*KN

typedef unsigned short u16;
typedef unsigned int u32;

typedef __bf16 bf16x8 __attribute__((ext_vector_type(8)));
typedef float f32x16 __attribute__((ext_vector_type(16)));

__device__ inline u16 f2bf(float f) {
    u32 u = __builtin_bit_cast(u32, f);
    u32 r = (u + 0x7FFFu + ((u >> 16) & 1u)) >> 16;  // RNE
    return (u16)r;
}

// global 16B/lane -> LDS at (wave-uniform base + lane*16); dest linear.
__device__ inline void gload_lds16(const void* g, void* l) {
    __builtin_amdgcn_global_load_lds(
        (const __attribute__((address_space(1))) u32*)g,
        (__attribute__((address_space(3))) u32*)l, 16, 0, 0);
}

// ---------------------------------------------------------------------------
// Kernel 1: transpose + bf16 cast:  x[b][c][n] f32  ->  xT[b][n][c] bf16
// ---------------------------------------------------------------------------
__global__ void transpose_x(const float* __restrict__ x, u16* __restrict__ xT) {
    __shared__ u16 tile[64][72];
    const int b = blockIdx.y;
    const int n0 = blockIdx.x * 64;
    const int tid = threadIdx.x;

#pragma unroll
    for (int i = 0; i < 16; ++i) {
        int flat = i * 256 + tid;
        int c = flat >> 6;
        int nn = flat & 63;
        int n = n0 + nn;
        if (n < NV) {
            float v = __builtin_nontemporal_load(&x[((size_t)b * CI + c) * NV + n]);
            tile[nn][c] = f2bf(v);
        }
    }
    __syncthreads();

#pragma unroll
    for (int i = 0; i < 2; ++i) {
        int flat8 = i * 256 + tid;
        int nn = flat8 >> 3;
        int c0 = (flat8 & 7) * 8;
        int n = n0 + nn;
        if (n < NV) {
            uint4 v = *(const uint4*)&tile[nn][c0];
            *(uint4*)&xT[((size_t)b * NV + n) * CI + c0] = v;
        }
    }
}

// ---------------------------------------------------------------------------
// Kernel 2: pack W into MFMA A-fragment order (bf16)
// Wf byte offset (rg*28 + k*4 + sub)*1024 + lane*16
// ---------------------------------------------------------------------------
__global__ void pack_w(const float* __restrict__ W, u16* __restrict__ Wf) {
    int e = blockIdx.x * 256 + threadIdx.x;
    if (e < 2 * 28 * 64 * 8) {
        int j = e & 7;
        int lane = (e >> 3) & 63;
        int sg = e >> 9;
        int s = sg % 28;
        int rg = sg / 28;
        int o = rg * 32 + (lane & 31);
        int kk = s * 16 + ((lane >> 5) << 3) + j;
        int kn = kk >> 6;
        int c = kk & 63;
        Wf[e] = f2bf(W[o * KKD + c * KN + kn]);
    }
}

// ---------------------------------------------------------------------------
// Kernel 3: gather + MFMA GEMM, RING-4 (3-iteration prefetch flight).
// Single-variable change vs r7 (53.8 us): G staged k+3 ahead instead of k+2,
// so each gather has >= one full L3 round-trip (~600-900 cyc) of flight
// before its forced drain. WAR distance UNCHANGED: slot (k+3)&3 == (k-1)&3,
// i.e. stage-after-barrier overwrites the slot read at iter k-1 -- exactly
// the r6/r7-proven schedule, so the race proof carries over.
// grid 1-D: b = bid&7 (XCD pin), n0 = (bid>>3)*64. block 256 = 4 waves
// (2 rg x 2 cg); wave = 32 outputs x 32 vertices, 4 MFMA per k.
// LDS: G[4][8KB] ring (32 KB) -> 5 blocks/CU.
// Per iter k: issue A(k+1)4 -> WAIT(ladder) -> s_barrier -> stage G(k+3)2
// -> compute slot k&3.
// Exact ladder (queue walk): [8,6,6,6,6,4,0].
// ---------------------------------------------------------------------------
__global__ __launch_bounds__(256, 5) void conv_mfma(
    const u16* __restrict__ xT, const u16* __restrict__ Wf,
    const int* __restrict__ idx, const float* __restrict__ bias,
    float* __restrict__ out) {
    __shared__ alignas(16) u16 G[4][4096];   // ring-4 x 8 KB

    const int bid = blockIdx.x;
    const int b = bid & 7;
    const int n0 = (bid >> 3) * 64;
    const int t = threadIdx.x;
    const int lane = t & 63;
    const int w = t >> 6;        // 0..3
    const int rg = w & 1;
    const int cg = w >> 1;       // 0..1
    const int col = lane & 31;
    const int half = lane >> 5;

    const char* xbc = (const char*)(xT + (size_t)b * NV * CI);
    const char* wfc = (const char*)Wf;

    // staging geometry: thread t covers rows sr0 and 32+sr0, chunk q
    const int sr0 = t >> 3;                // 0..31
    const int q = t & 7;
    const int qe = q ^ (sr0 & 7);          // source pre-swizzle ((sr0+32)&7 == sr0&7)

    int g0 = n0 + sr0;        if (g0 >= NV) g0 = NV - 1;
    int g1 = n0 + 32 + sr0;   if (g1 >= NV) g1 = NV - 1;

    // all 7 neighbor indices per row (overlapping dwordx4 loads)
    int j0[KN], j1[KN];
    {
        int4 lo0 = *(const int4*)(idx + (size_t)g0 * KN);
        int4 hi0 = *(const int4*)(idx + (size_t)g0 * KN + 3);
        int4 lo1 = *(const int4*)(idx + (size_t)g1 * KN);
        int4 hi1 = *(const int4*)(idx + (size_t)g1 * KN + 3);
        j0[0] = lo0.x; j0[1] = lo0.y; j0[2] = lo0.z; j0[3] = lo0.w;
        j0[4] = hi0.y; j0[5] = hi0.z; j0[6] = hi0.w;
        j1[0] = lo1.x; j1[1] = lo1.y; j1[2] = lo1.z; j1[3] = lo1.w;
        j1[4] = hi1.y; j1[5] = hi1.z; j1[6] = hi1.w;
    }

    // per-wave LDS dest bases (wave-uniform); buffer = 64 rows x 128 B
    char* gb = (char*)&G[0][0];
    const u32 dst0 = (u32)(w * 1024);            // rows 0..31 slice
    const u32 dst1 = (u32)(4096 + w * 1024);     // rows 32..63 slice

    // B-read geometry
    const int brow = cg * 32 + col;              // 0..63
    const u32 rbase = (u32)(brow * 128);
    const u32 rmask = (u32)(brow & 7) << 4;

    // A-frag addresses
    const u32 abase = (u32)((rg * 28) * 1024 + lane * 16);

    f32x16 acc{};

    // ---- prologue: G(0), A(0), G(1), G(2)  (issue order pinned) ----
    gload_lds16(xbc + (size_t)j0[0] * 128 + qe * 16, gb + 0 * 8192 + dst0);
    gload_lds16(xbc + (size_t)j1[0] * 128 + qe * 16, gb + 0 * 8192 + dst1);
    __builtin_amdgcn_sched_barrier(0);
    uint4 acur0 = *(const uint4*)(wfc + abase + 0 * 1024);
    uint4 acur1 = *(const uint4*)(wfc + abase + 1 * 1024);
    uint4 acur2 = *(const uint4*)(wfc + abase + 2 * 1024);
    uint4 acur3 = *(const uint4*)(wfc + abase + 3 * 1024);
    __builtin_amdgcn_sched_barrier(0);
    gload_lds16(xbc + (size_t)j0[1] * 128 + qe * 16, gb + 1 * 8192 + dst0);
    gload_lds16(xbc + (size_t)j1[1] * 128 + qe * 16, gb + 1 * 8192 + dst1);
    gload_lds16(xbc + (size_t)j0[2] * 128 + qe * 16, gb + 2 * 8192 + dst0);
    gload_lds16(xbc + (size_t)j1[2] * 128 + qe * 16, gb + 2 * 8192 + dst1);
    __builtin_amdgcn_sched_barrier(0);

#pragma unroll
    for (int k = 0; k < KN; ++k) {
        // ---- issue A(k+1) (pre-wait; consumed next iter) ----
        uint4 an0, an1, an2, an3;
        if (k + 1 < KN) {
            u32 ab = abase + (u32)((k + 1) * 4 * 1024);
            an0 = *(const uint4*)(wfc + ab + 0 * 1024);
            an1 = *(const uint4*)(wfc + ab + 1 * 1024);
            an2 = *(const uint4*)(wfc + ab + 2 * 1024);
            an3 = *(const uint4*)(wfc + ab + 3 * 1024);
        }
        __builtin_amdgcn_sched_barrier(0);

        // ---- exact ladder [8,6,6,6,6,4,0]: drains G(k)+A(k), keeps rest ----
        if (k == 0)      asm volatile("s_waitcnt vmcnt(8)" ::: "memory");
        else if (k <= 4) asm volatile("s_waitcnt vmcnt(6)" ::: "memory");
        else if (k == 5) asm volatile("s_waitcnt vmcnt(4)" ::: "memory");
        else             asm volatile("s_waitcnt vmcnt(0)" ::: "memory");
        __builtin_amdgcn_sched_barrier(0);
        __builtin_amdgcn_s_barrier();
        __builtin_amdgcn_sched_barrier(0);

        // ---- stage G(k+3) AFTER barrier into slot (k+3)&3 == (k-1)&3:
        //      that slot's readers (iter k-1) finished before barrier k ----
        if (k + 3 < KN) {
            u32 db = (u32)(((k + 3) & 3) * 8192);
            gload_lds16(xbc + (size_t)j0[k + 3] * 128 + qe * 16, gb + db + dst0);
            gload_lds16(xbc + (size_t)j1[k + 3] * 128 + qe * 16, gb + db + dst1);
        }
        __builtin_amdgcn_sched_barrier(0);

        // ---- compute on slot k&3 ----
        const char* gsrc = gb + (u32)((k & 3) * 8192);
#pragma unroll
        for (int s = 0; s < 4; ++s) {
            u32 boff = rbase + ((((u32)s * 32) + (u32)half * 16) ^ rmask);
            uint4 bf = *(const uint4*)(gsrc + boff);
            uint4 af = (s == 0) ? acur0 : (s == 1) ? acur1 : (s == 2) ? acur2 : acur3;
            acc = __builtin_amdgcn_mfma_f32_32x32x16_bf16(
                __builtin_bit_cast(bf16x8, af),
                __builtin_bit_cast(bf16x8, bf), acc, 0, 0, 0);
        }

        if (k + 1 < KN) { acur0 = an0; acur1 = an1; acur2 = an2; acur3 = an3; }
    }

    // epilogue: bias + plain stores (contiguous 128B runs)
    const int v = n0 + cg * 32 + col;
    if (v < NV) {
        float* ob = out + (size_t)b * CO * NV + v;
#pragma unroll
        for (int r = 0; r < 16; ++r) {
            int rowo = (r & 3) + 8 * (r >> 2) + 4 * half;
            int o = rg * 32 + rowo;
            ob[(size_t)o * NV] = acc[r] + bias[o];
        }
    }
}

// ---------------------------------------------------------------------------
// Fallback (if ws too small): direct fp32 compute, slow but correct.
// ---------------------------------------------------------------------------
__global__ void naive_conv(const float* __restrict__ x, const int* __restrict__ idx,
                           const float* __restrict__ W, const float* __restrict__ bias,
                           float* __restrict__ out) {
    const int b = blockIdx.y;
    const int n = blockIdx.x * 4 + (threadIdx.x & 3);
    const int o = threadIdx.x >> 2;
    if (n >= NV) return;
    float acc = bias[o];
    const float* xb = x + (size_t)b * CI * NV;
    const float* wo = W + o * KKD;
    for (int k = 0; k < KN; ++k) {
        int j = idx[n * KN + k];
        for (int c = 0; c < CI; ++c)
            acc += xb[(size_t)c * NV + j] * wo[c * KN + k];
    }
    out[((size_t)b * CO + o) * NV + n] = acc;
}

// ---------------------------------------------------------------------------
extern "C" void kernel_launch(void* const* d_in, const int* in_sizes, int n_in,
                              void* d_out, int out_size, void* d_ws, size_t ws_size,
                              hipStream_t stream) {
    const float* x    = (const float*)d_in[0];
    const int*   idx  = (const int*)d_in[1];
    const float* W    = (const float*)d_in[2];
    const float* bias = (const float*)d_in[3];
    float* out = (float*)d_out;

    const size_t xT_bytes = (size_t)BB * NV * CI * 2;       // 41,945,088
    const size_t wf_bytes = (size_t)2 * 28 * 64 * 8 * 2;    // 57,344
    const size_t need = xT_bytes + wf_bytes;

    if (ws_size >= need) {
        u16* xT = (u16*)d_ws;
        u16* Wf = (u16*)((char*)d_ws + xT_bytes);
        transpose_x<<<dim3((NV + 63) / 64, BB), 256, 0, stream>>>(x, xT);
        pack_w<<<dim3(112), 256, 0, stream>>>(W, Wf);
        const int ntiles = (NV + 63) / 64;                   // 641
        conv_mfma<<<dim3(ntiles * BB), 256, 0, stream>>>(xT, Wf, idx, bias, out);
    } else {
        naive_conv<<<dim3((NV + 3) / 4, BB), 256, 0, stream>>>(x, idx, W, bias, out);
    }
}